// Round 8
// baseline (13498.909 us; speedup 1.0000x reference)
//
#include <hip/hip_runtime.h>
#include <math.h>

#define HH   1080
#define WW   1920
#define NPIX (HH*WW)          // 2073600
#define MAXP 2048
#define NTHR 256
#define NWAVE (NTHR/64)       // 4
#define PPB  4096             // points per block (contiguous chunk), = NTHR*KPT
#define KPT  16
#define NBLK 507              // 507*4096 = 2076672 >= NPIX; block 506 partially padded

#define CXF 960.0f
#define CYF 540.0f
#define FXF 1050.0f
#define FYF 1050.0f

// per-iteration, per-block communication slots (zeroed each call by zero_ws_kernel)
__device__ unsigned long long g_packed[MAXP * NBLK];  // (dist_bits<<32 | ~idx), 0 = sentinel
__device__ float              g_z[MAXP * NBLK];       // candidate depth, 0.0f = sentinel

__device__ __forceinline__ float proj_x(float u, float d) {
    return __fdiv_rn(__fmul_rn(__fsub_rn(u, CXF), d), FXF);
}
__device__ __forceinline__ float proj_y(float v, float d) {
    return __fdiv_rn(__fmul_rn(__fsub_rn(v, CYF), d), FYF);
}
__device__ __forceinline__ unsigned long long umax64(unsigned long long a, unsigned long long b) {
    return a > b ? a : b;
}

__global__ void zero_ws_kernel() {
    unsigned i = blockIdx.x * 256u + threadIdx.x;
    if (i < (unsigned)(MAXP * NBLK)) { g_packed[i] = 0ull; g_z[i] = 0.0f; }
}

__global__ __attribute__((amdgpu_flat_work_group_size(NTHR, NTHR)))
void fps_kernel(const float* __restrict__ depth, const float* __restrict__ rgb,
                float* __restrict__ out)
{
    const unsigned tid  = threadIdx.x;
    const unsigned lane = threadIdx.x & 63u;
    const unsigned wid  = threadIdx.x >> 6;
    const unsigned blk  = blockIdx.x;
    const unsigned base = blk << 12;            // first pixel owned by this block
    const float FINF = __int_as_float(0x7f800000);

    // ---- LDS-resident point state (allocator-proof) ----
    __shared__ float2 sXY[PPB];                 // 32 KB  (x, y)
    __shared__ float2 sZD[PPB];                 // 32 KB  (z, running min-dist)
    __shared__ unsigned long long s_pp[NWAVE];
    __shared__ float              s_pz[NWAVE];
    __shared__ unsigned long long s_gp[2];
    __shared__ float              s_d[512];     // winner-z per block (indexed by wblk)
    __shared__ unsigned           s_widx[MAXP]; // block 0 only: selected indices

    // ---- init: project owned pixels into LDS (coalesced depth loads) ----
    #pragma unroll
    for (int j = 0; j < KPT; ++j) {
        unsigned o   = tid + (unsigned)j * NTHR;
        unsigned idx = base + o;
        float x, y, z, dd;
        if (idx < NPIX) {
            float d = depth[idx];
            float u = (float)(idx % WW);
            float v = (float)(idx / WW);
            bool val = (d > 0.1f) && (d < 2.0f) && __builtin_isfinite(d);
            x = val ? proj_x(u, d) : FINF;
            y = val ? proj_y(v, d) : FINF;
            z = val ? d : FINF;
            dd = FINF;
        } else { x = 0.f; y = 0.f; z = 0.f; dd = -1.0f; }  // pad: never selected
        sXY[o] = make_float2(x, y);
        sZD[o] = make_float2(z, dd);
    }
    if (tid == 0) s_widx[0] = 0u;
    __syncthreads();   // LDS state visible to all waves before iterating

    // first FPS point = flat index 0
    float px, py, pz;
    {
        float d = depth[0];
        bool val = (d > 0.1f) && (d < 2.0f) && __builtin_isfinite(d);
        px = val ? proj_x(0.0f, d) : FINF;
        py = val ? proj_y(0.0f, d) : FINF;
        pz = val ? d : FINF;
    }

    for (int it = 1; it < MAXP; ++it) {
        // ---- LDS distance update + thread-local argmax ----
        // descending j + ">=" keeps the LOWEST pixel index on ties (np.argmax)
        float bestd = -2.0f, bestz = 0.0f;
        unsigned besti = 0u;
        #pragma unroll
        for (int j = KPT - 1; j >= 0; --j) {
            unsigned o  = tid + (unsigned)j * NTHR;
            float2 xy = sXY[o];
            float2 zd = sZD[o];
            float dx = __fsub_rn(xy.x, px);
            float dy = __fsub_rn(xy.y, py);
            float dz = __fsub_rn(zd.x, pz);
            float s  = __fadd_rn(__fadd_rn(__fmul_rn(dx, dx), __fmul_rn(dy, dy)),
                                 __fmul_rn(dz, dz));
            float nd = fminf(zd.y, s);
            sZD[o] = make_float2(zd.x, nd);
            if (nd >= bestd) { bestd = nd; besti = base + o; bestz = zd.x; }
        }

        unsigned long long pk =
            ((unsigned long long)__float_as_uint(bestd) << 32) |
            (unsigned long long)(~besti);
        float zz = bestz;

        // ---- wave reduce (max on packed, carry z) ----
        #pragma unroll
        for (int off = 32; off; off >>= 1) {
            unsigned long long o  = __shfl_xor(pk, off);
            float              oz = __shfl_xor(zz, off);
            if (o > pk) { pk = o; zz = oz; }
        }
        if (lane == 0) { s_pp[wid] = pk; s_pz[wid] = zz; }
        __syncthreads();

        // ---- wave 0: block reduce + relaxed write-through stores (no fences) ----
        if (wid == 0) {
            unsigned long long p2 = s_pp[lane & 3u];
            float              z2 = s_pz[lane & 3u];
            #pragma unroll
            for (int off = 2; off; off >>= 1) {
                unsigned long long o  = __shfl_xor(p2, off);
                float              oz = __shfl_xor(z2, off);
                if (o > p2) { p2 = o; z2 = oz; }
            }
            if (lane == 0) {
                __hip_atomic_store(&g_z[(size_t)it * NBLK + blk], z2,
                                   __ATOMIC_RELAXED, __HIP_MEMORY_SCOPE_AGENT);
                __hip_atomic_store(&g_packed[(size_t)it * NBLK + blk], p2,
                                   __ATOMIC_RELAXED, __HIP_MEMORY_SCOPE_AGENT);
            }
        }

        // ---- one concurrent poll round: waves 0-1 poll packed, waves 2-3 poll z ----
        if (wid < 2) {
            unsigned long long vmax = 0ull;
            #pragma unroll
            for (int r = 0; r < 4; ++r) {
                unsigned slot = (unsigned)r * 128u + wid * 64u + lane;
                if (slot < NBLK) {
                    const unsigned long long* ap = &g_packed[(size_t)it * NBLK + slot];
                    unsigned long long v;
                    for (;;) {
                        v = __hip_atomic_load(ap, __ATOMIC_RELAXED, __HIP_MEMORY_SCOPE_AGENT);
                        if (v != 0ull) break;
                        __builtin_amdgcn_s_sleep(1);
                    }
                    vmax = umax64(vmax, v);
                }
            }
            #pragma unroll
            for (int off = 32; off; off >>= 1) vmax = umax64(vmax, __shfl_xor(vmax, off));
            if (lane == 0) s_gp[wid] = vmax;
        } else {
            #pragma unroll
            for (int r = 0; r < 4; ++r) {
                unsigned slot = (unsigned)r * 128u + (wid - 2u) * 64u + lane;
                if (slot < NBLK) {
                    const float* ad = &g_z[(size_t)it * NBLK + slot];
                    float zv;
                    for (;;) {
                        zv = __hip_atomic_load(ad, __ATOMIC_RELAXED, __HIP_MEMORY_SCOPE_AGENT);
                        if (zv != 0.0f) break;
                        __builtin_amdgcn_s_sleep(1);
                    }
                    s_d[slot] = zv;
                }
            }
        }
        __syncthreads();

        // ---- everyone computes the winner locally; reconstruct its xyz ----
        unsigned long long w = umax64(s_gp[0], s_gp[1]);
        unsigned widx = ~((unsigned)(w & 0xFFFFFFFFull));
        unsigned wblk = widx >> 12;                 // owner block (contiguous chunks)
        float    wd   = s_d[wblk];
        if (blk == 0 && tid == 0) s_widx[it] = widx;

        float uu = (float)(widx % WW);
        float vv = (float)(widx / WW);
        bool val = (wd > 0.1f) && (wd < 2.0f) && __builtin_isfinite(wd);
        px = val ? proj_x(uu, wd) : FINF;
        py = val ? proj_y(vv, wd) : FINF;
        pz = val ? wd : FINF;
    }

    // ---- epilogue: block 0 gathers, normalizes, writes [2048,9] ----
    if (blk == 0) {
        __syncthreads();
        float ex[8], ey[8], ez[8], er[8], eg[8], eb[8];
        #pragma unroll
        for (int q = 0; q < 8; ++q) {
            int i = (int)tid + q * NTHR;
            unsigned sidx = s_widx[i];
            float d = depth[sidx];
            float u = (float)(sidx % WW);
            float v = (float)(sidx / WW);
            bool val = (d > 0.1f) && (d < 2.0f) && __builtin_isfinite(d);
            ex[q] = val ? proj_x(u, d) : FINF;
            ey[q] = val ? proj_y(v, d) : FINF;
            ez[q] = val ? d : FINF;
            er[q] = val ? __fdiv_rn(rgb[3u * sidx + 0u], 255.0f) : 0.0f;
            eg[q] = val ? __fdiv_rn(rgb[3u * sidx + 1u], 255.0f) : 0.0f;
            eb[q] = val ? __fdiv_rn(rgb[3u * sidx + 2u], 255.0f) : 0.0f;
        }
        float mn[3], mx[3];
        mn[0] = ex[0]; mx[0] = ex[0];
        mn[1] = ey[0]; mx[1] = ey[0];
        mn[2] = ez[0]; mx[2] = ez[0];
        #pragma unroll
        for (int q = 1; q < 8; ++q) {
            mn[0] = fminf(mn[0], ex[q]); mx[0] = fmaxf(mx[0], ex[q]);
            mn[1] = fminf(mn[1], ey[q]); mx[1] = fmaxf(mx[1], ey[q]);
            mn[2] = fminf(mn[2], ez[q]); mx[2] = fmaxf(mx[2], ez[q]);
        }
        #pragma unroll
        for (int c = 0; c < 3; ++c) {
            for (int off = 32; off > 0; off >>= 1) {
                mn[c] = fminf(mn[c], __shfl_xor(mn[c], off));
                mx[c] = fmaxf(mx[c], __shfl_xor(mx[c], off));
            }
        }
        __shared__ float s_mn[NWAVE][3], s_mx[NWAVE][3];
        __shared__ float f_mn[3], f_sc[3];
        if (lane == 0) {
            for (int c = 0; c < 3; ++c) { s_mn[wid][c] = mn[c]; s_mx[wid][c] = mx[c]; }
        }
        __syncthreads();
        if (wid == 0) {
            float a[3], b[3];
            for (int c = 0; c < 3; ++c) {
                a[c] = (lane < NWAVE) ? s_mn[lane][c] : FINF;
                b[c] = (lane < NWAVE) ? s_mx[lane][c] : -FINF;
            }
            for (int off = NWAVE / 2; off > 0; off >>= 1) {
                for (int c = 0; c < 3; ++c) {
                    a[c] = fminf(a[c], __shfl_xor(a[c], off));
                    b[c] = fmaxf(b[c], __shfl_xor(b[c], off));
                }
            }
            if (lane == 0) {
                for (int c = 0; c < 3; ++c) {
                    f_mn[c] = a[c];
                    float m = __fsub_rn(b[c], a[c]);   // == max(centered) by monotonicity
                    f_sc[c] = (m < 1e-8f) ? 1.0f : m;
                }
            }
        }
        __syncthreads();
        float MN0 = f_mn[0], MN1 = f_mn[1], MN2 = f_mn[2];
        float SC0 = f_sc[0], SC1 = f_sc[1], SC2 = f_sc[2];
        #pragma unroll
        for (int q = 0; q < 8; ++q) {
            int i = (int)tid + q * NTHR;
            out[9 * i + 0] = ex[q];
            out[9 * i + 1] = ey[q];
            out[9 * i + 2] = ez[q];
            out[9 * i + 3] = er[q];
            out[9 * i + 4] = eg[q];
            out[9 * i + 5] = eb[q];
            out[9 * i + 6] = __fdiv_rn(__fsub_rn(ex[q], MN0), SC0);
            out[9 * i + 7] = __fdiv_rn(__fsub_rn(ey[q], MN1), SC1);
            out[9 * i + 8] = __fdiv_rn(__fsub_rn(ez[q], MN2), SC2);
        }
    }
}

extern "C" void kernel_launch(void* const* d_in, const int* in_sizes, int n_in,
                              void* d_out, int out_size, void* d_ws, size_t ws_size,
                              hipStream_t stream) {
    const float* depth = (const float*)d_in[0];
    const float* rgb   = (const float*)d_in[1];
    float* out = (float*)d_out;

    // re-initialize communication slots (deterministic per call / per graph replay)
    zero_ws_kernel<<<dim3((MAXP * NBLK + 255) / 256), dim3(256), 0, stream>>>();

    void* args[] = { (void*)&depth, (void*)&rgb, (void*)&out };
    hipLaunchCooperativeKernel((const void*)fps_kernel, dim3(NBLK), dim3(NTHR),
                               args, 0, stream);
}

// Round 9
// 11423.135 us; speedup vs baseline: 1.1817x; 1.1817x over previous
//
#include <hip/hip_runtime.h>
#include <math.h>

#define HH   1080
#define WW   1920
#define NPIX (HH*WW)          // 2073600
#define MAXP 2048
#define NTHR 512
#define NWAVE (NTHR/64)       // 8
#define PPB  8192             // points per block (contiguous slab) = NTHR*KPT
#define KPT  16
#define NBLK 254              // 254*8192 = 2080768 >= NPIX; block 253 partially padded

#define CXF 960.0f
#define CYF 540.0f
#define FXF 1050.0f
#define FYF 1050.0f

// per-iteration, per-block communication slots (zeroed each call by zero_ws_kernel)
__device__ unsigned long long g_packed[MAXP * NBLK];  // (dist_bits<<32 | ~idx), 0 = sentinel
__device__ float              g_z[MAXP * NBLK];       // candidate depth, 0.0f = sentinel

__device__ __forceinline__ float proj_x(float u, float d) {
    return __fdiv_rn(__fmul_rn(__fsub_rn(u, CXF), d), FXF);
}
__device__ __forceinline__ float proj_y(float v, float d) {
    return __fdiv_rn(__fmul_rn(__fsub_rn(v, CYF), d), FYF);
}
__device__ __forceinline__ unsigned long long umax64(unsigned long long a, unsigned long long b) {
    return a > b ? a : b;
}

__global__ void zero_ws_kernel() {
    unsigned i = blockIdx.x * 256u + threadIdx.x;
    if (i < (unsigned)(MAXP * NBLK)) { g_packed[i] = 0ull; g_z[i] = 0.0f; }
}

// ---- mutable state (running min-dists): 16 named loop-carried registers.
// Rounds 2-7 proved the allocator keeps exactly these resident (VGPR=56 = 16 D + working).
#define FOR16(M)  M(0) M(1) M(2) M(3) M(4) M(5) M(6) M(7) M(8) M(9) M(10) M(11) M(12) M(13) M(14) M(15)
#define FOR16D(M) M(15) M(14) M(13) M(12) M(11) M(10) M(9) M(8) M(7) M(6) M(5) M(4) M(3) M(2) M(1) M(0)
#define DECLD(j) float D##j;

// descending j + ">=" keeps the LOWEST global index on distance ties (np.argmax).
// Pad points carry D=-1: every thread owns >=2 real points (dist>=0), and pads are
// visited first in the descending scan, so a pad can never survive as the winner.
#define UPDJ(j) { \
    unsigned o = tid + j##u * (unsigned)NTHR; \
    float4 P = sP[o]; \
    float dx = __fsub_rn(P.x, px); \
    float dy = __fsub_rn(P.y, py); \
    float dz = __fsub_rn(P.z, pz); \
    float s  = __fadd_rn(__fadd_rn(__fmul_rn(dx, dx), __fmul_rn(dy, dy)), __fmul_rn(dz, dz)); \
    float nd = fminf(D##j, s); \
    D##j = nd; \
    if (nd >= bestd) { bestd = nd; besti = base + o; bestz = P.z; } }

__global__ __attribute__((amdgpu_flat_work_group_size(NTHR, NTHR)))
void fps_kernel(const float* __restrict__ depth, const float* __restrict__ rgb,
                float* __restrict__ out)
{
    const unsigned tid  = threadIdx.x;
    const unsigned lane = threadIdx.x & 63u;
    const unsigned wid  = threadIdx.x >> 6;
    const unsigned blk  = blockIdx.x;
    const unsigned base = blk << 13;            // first pixel owned by this block
    const float FINF = __int_as_float(0x7f800000);

    // ---- immutable xyz in LDS (one ds_read_b128 per point per iteration) ----
    __shared__ float4 sP[PPB];                  // 128 KB
    __shared__ unsigned long long s_pp[NWAVE];
    __shared__ float              s_pz[NWAVE];
    __shared__ unsigned long long s_gp[4];
    __shared__ float              s_d[256];     // winner-z per block (indexed by wblk)
    __shared__ unsigned           s_widx[MAXP]; // block 0 only: selected indices

    FOR16(DECLD)

    // ---- init: project owned pixels into LDS (coalesced depth loads) ----
    #define INITJ(j) { \
        unsigned o   = tid + j##u * (unsigned)NTHR; \
        unsigned idx = base + o; \
        float x, y, z; \
        if (idx < NPIX) { \
            float d = depth[idx]; \
            float u = (float)(idx % WW); \
            float v = (float)(idx / WW); \
            bool val = (d > 0.1f) && (d < 2.0f) && __builtin_isfinite(d); \
            x = val ? proj_x(u, d) : FINF; \
            y = val ? proj_y(v, d) : FINF; \
            z = val ? d : FINF; \
            D##j = FINF; \
        } else { x = 0.f; y = 0.f; z = 0.f; D##j = -1.0f; } \
        sP[o] = make_float4(x, y, z, 0.0f); }
    FOR16(INITJ)

    if (tid == 0) s_widx[0] = 0u;
    __syncthreads();   // LDS xyz visible to all waves before iterating

    // first FPS point = flat index 0
    float px, py, pz;
    {
        float d = depth[0];
        bool val = (d > 0.1f) && (d < 2.0f) && __builtin_isfinite(d);
        px = val ? proj_x(0.0f, d) : FINF;
        py = val ? proj_y(0.0f, d) : FINF;
        pz = val ? d : FINF;
    }

    for (int it = 1; it < MAXP; ++it) {
        // ---- distance update (LDS xyz + register D) + thread-local argmax ----
        float bestd = -2.0f, bestz = 0.0f;
        unsigned besti = 0u;
        FOR16D(UPDJ)

        unsigned long long pk =
            ((unsigned long long)__float_as_uint(bestd) << 32) |
            (unsigned long long)(~besti);
        float zz = bestz;

        // ---- wave reduce (max on packed, carry z) ----
        #pragma unroll
        for (int off = 32; off; off >>= 1) {
            unsigned long long o  = __shfl_xor(pk, off);
            float              oz = __shfl_xor(zz, off);
            if (o > pk) { pk = o; zz = oz; }
        }
        if (lane == 0) { s_pp[wid] = pk; s_pz[wid] = zz; }
        __syncthreads();

        // ---- wave 0: block reduce + relaxed write-through stores (no fences) ----
        if (wid == 0) {
            unsigned long long p2 = s_pp[lane & 7u];
            float              z2 = s_pz[lane & 7u];
            #pragma unroll
            for (int off = 4; off; off >>= 1) {
                unsigned long long o  = __shfl_xor(p2, off);
                float              oz = __shfl_xor(z2, off);
                if (o > p2) { p2 = o; z2 = oz; }
            }
            if (lane == 0) {
                __hip_atomic_store(&g_z[(size_t)it * NBLK + blk], z2,
                                   __ATOMIC_RELAXED, __HIP_MEMORY_SCOPE_AGENT);
                __hip_atomic_store(&g_packed[(size_t)it * NBLK + blk], p2,
                                   __ATOMIC_RELAXED, __HIP_MEMORY_SCOPE_AGENT);
            }
        }

        // ---- one concurrent poll round: waves 0-3 poll packed, waves 4-7 poll z ----
        if (wid < 4) {
            unsigned slot = wid * 64u + lane;
            unsigned long long v = 0ull;
            if (slot < NBLK) {
                const unsigned long long* ap = &g_packed[(size_t)it * NBLK + slot];
                for (;;) {
                    v = __hip_atomic_load(ap, __ATOMIC_RELAXED, __HIP_MEMORY_SCOPE_AGENT);
                    if (v != 0ull) break;
                    __builtin_amdgcn_s_sleep(1);
                }
            }
            #pragma unroll
            for (int off = 32; off; off >>= 1) v = umax64(v, __shfl_xor(v, off));
            if (lane == 0) s_gp[wid] = v;
        } else {
            unsigned slot = (wid - 4u) * 64u + lane;
            if (slot < NBLK) {
                const float* ad = &g_z[(size_t)it * NBLK + slot];
                float zv;
                for (;;) {
                    zv = __hip_atomic_load(ad, __ATOMIC_RELAXED, __HIP_MEMORY_SCOPE_AGENT);
                    if (zv != 0.0f) break;
                    __builtin_amdgcn_s_sleep(1);
                }
                s_d[slot] = zv;
            }
        }
        __syncthreads();

        // ---- everyone computes the winner locally; reconstruct its xyz ----
        unsigned long long w = umax64(umax64(s_gp[0], s_gp[1]), umax64(s_gp[2], s_gp[3]));
        unsigned widx = ~((unsigned)(w & 0xFFFFFFFFull));
        unsigned wblk = widx >> 13;                 // owner block (8192-pt slabs)
        float    wd   = s_d[wblk];
        if (blk == 0 && tid == 0) s_widx[it] = widx;

        float uu = (float)(widx % WW);
        float vv = (float)(widx / WW);
        bool val = (wd > 0.1f) && (wd < 2.0f) && __builtin_isfinite(wd);
        px = val ? proj_x(uu, wd) : FINF;
        py = val ? proj_y(vv, wd) : FINF;
        pz = val ? wd : FINF;
    }

    // ---- epilogue: block 0 gathers, normalizes, writes [2048,9] ----
    if (blk == 0) {
        __syncthreads();
        float ex[4], ey[4], ez[4], er[4], eg[4], eb[4];
        #pragma unroll
        for (int q = 0; q < 4; ++q) {
            int i = (int)tid + q * NTHR;
            unsigned sidx = s_widx[i];
            float d = depth[sidx];
            float u = (float)(sidx % WW);
            float v = (float)(sidx / WW);
            bool val = (d > 0.1f) && (d < 2.0f) && __builtin_isfinite(d);
            ex[q] = val ? proj_x(u, d) : FINF;
            ey[q] = val ? proj_y(v, d) : FINF;
            ez[q] = val ? d : FINF;
            er[q] = val ? __fdiv_rn(rgb[3u * sidx + 0u], 255.0f) : 0.0f;
            eg[q] = val ? __fdiv_rn(rgb[3u * sidx + 1u], 255.0f) : 0.0f;
            eb[q] = val ? __fdiv_rn(rgb[3u * sidx + 2u], 255.0f) : 0.0f;
        }
        float mn[3], mx[3];
        mn[0] = fminf(fminf(ex[0], ex[1]), fminf(ex[2], ex[3]));
        mx[0] = fmaxf(fmaxf(ex[0], ex[1]), fmaxf(ex[2], ex[3]));
        mn[1] = fminf(fminf(ey[0], ey[1]), fminf(ey[2], ey[3]));
        mx[1] = fmaxf(fmaxf(ey[0], ey[1]), fmaxf(ey[2], ey[3]));
        mn[2] = fminf(fminf(ez[0], ez[1]), fminf(ez[2], ez[3]));
        mx[2] = fmaxf(fmaxf(ez[0], ez[1]), fmaxf(ez[2], ez[3]));
        #pragma unroll
        for (int c = 0; c < 3; ++c) {
            for (int off = 32; off > 0; off >>= 1) {
                mn[c] = fminf(mn[c], __shfl_xor(mn[c], off));
                mx[c] = fmaxf(mx[c], __shfl_xor(mx[c], off));
            }
        }
        __shared__ float s_mn[NWAVE][3], s_mx[NWAVE][3];
        __shared__ float f_mn[3], f_sc[3];
        if (lane == 0) {
            for (int c = 0; c < 3; ++c) { s_mn[wid][c] = mn[c]; s_mx[wid][c] = mx[c]; }
        }
        __syncthreads();
        if (wid == 0) {
            float a[3], b[3];
            for (int c = 0; c < 3; ++c) {
                a[c] = (lane < NWAVE) ? s_mn[lane][c] : FINF;
                b[c] = (lane < NWAVE) ? s_mx[lane][c] : -FINF;
            }
            for (int off = NWAVE / 2; off > 0; off >>= 1) {
                for (int c = 0; c < 3; ++c) {
                    a[c] = fminf(a[c], __shfl_xor(a[c], off));
                    b[c] = fmaxf(b[c], __shfl_xor(b[c], off));
                }
            }
            if (lane == 0) {
                for (int c = 0; c < 3; ++c) {
                    f_mn[c] = a[c];
                    float m = __fsub_rn(b[c], a[c]);   // == max(centered) by monotonicity
                    f_sc[c] = (m < 1e-8f) ? 1.0f : m;
                }
            }
        }
        __syncthreads();
        float MN0 = f_mn[0], MN1 = f_mn[1], MN2 = f_mn[2];
        float SC0 = f_sc[0], SC1 = f_sc[1], SC2 = f_sc[2];
        #pragma unroll
        for (int q = 0; q < 4; ++q) {
            int i = (int)tid + q * NTHR;
            out[9 * i + 0] = ex[q];
            out[9 * i + 1] = ey[q];
            out[9 * i + 2] = ez[q];
            out[9 * i + 3] = er[q];
            out[9 * i + 4] = eg[q];
            out[9 * i + 5] = eb[q];
            out[9 * i + 6] = __fdiv_rn(__fsub_rn(ex[q], MN0), SC0);
            out[9 * i + 7] = __fdiv_rn(__fsub_rn(ey[q], MN1), SC1);
            out[9 * i + 8] = __fdiv_rn(__fsub_rn(ez[q], MN2), SC2);
        }
    }
}

extern "C" void kernel_launch(void* const* d_in, const int* in_sizes, int n_in,
                              void* d_out, int out_size, void* d_ws, size_t ws_size,
                              hipStream_t stream) {
    const float* depth = (const float*)d_in[0];
    const float* rgb   = (const float*)d_in[1];
    float* out = (float*)d_out;

    // re-initialize communication slots (deterministic per call / per graph replay)
    zero_ws_kernel<<<dim3((MAXP * NBLK + 255) / 256), dim3(256), 0, stream>>>();

    void* args[] = { (void*)&depth, (void*)&rgb, (void*)&out };
    hipLaunchCooperativeKernel((const void*)fps_kernel, dim3(NBLK), dim3(NTHR),
                               args, 0, stream);
}

// Round 10
// 8605.264 us; speedup vs baseline: 1.5687x; 1.3275x over previous
//
#include <hip/hip_runtime.h>
#include <math.h>

#define HH   1080
#define WW   1920
#define NPIX (HH*WW)          // 2073600 < 2^21
#define MAXP 2048
#define NTHR 512
#define NWAVE (NTHR/64)       // 8
#define PPB  8192             // points per block (contiguous slab) = NTHR*KPT
#define KPT  16
#define NBLK 254              // 254*8192 >= NPIX; block 253: 1024 real pts (2/thread)

#define CXF 960.0f
#define CYF 540.0f
#define FXF 1050.0f
#define FYF 1050.0f

// 53-bit sentinel slots: (dist_bits << 21) | (0x1FFFFF - idx). 0 == "not yet".
// (zeroed each call by zero_ws_kernel)
__device__ unsigned long long g_packed[MAXP * NBLK];

__device__ __forceinline__ float proj_x(float u, float d) {
    return __fdiv_rn(__fmul_rn(__fsub_rn(u, CXF), d), FXF);
}
__device__ __forceinline__ float proj_y(float v, float d) {
    return __fdiv_rn(__fmul_rn(__fsub_rn(v, CYF), d), FYF);
}
__device__ __forceinline__ unsigned long long umax64(unsigned long long a, unsigned long long b) {
    return a > b ? a : b;
}

__global__ void zero_ws_kernel() {
    unsigned i = blockIdx.x * 256u + threadIdx.x;
    if (i < (unsigned)(MAXP * NBLK)) g_packed[i] = 0ull;
}

// ---- mutable state (running min-dists): 16 named loop-carried registers ----
#define FOR16(M)  M(0) M(1) M(2) M(3) M(4) M(5) M(6) M(7) M(8) M(9) M(10) M(11) M(12) M(13) M(14) M(15)
#define FOR16D(M) M(15) M(14) M(13) M(12) M(11) M(10) M(9) M(8) M(7) M(6) M(5) M(4) M(3) M(2) M(1) M(0)
#define DECLD(j) float D##j;

// descending j + ">=" keeps the LOWEST global index on ties (np.argmax semantics).
// Pads carry D=-1 and are scanned first, so any real point (dist>=0) beats them;
// every thread owns >=2 real points, so bestd >= 0 always.
#define UPDJ(j) { \
    unsigned o = tid + j##u * (unsigned)NTHR; \
    float4 P = sP[o]; \
    float dx = __fsub_rn(P.x, px); \
    float dy = __fsub_rn(P.y, py); \
    float dz = __fsub_rn(P.z, pz); \
    float s  = __fadd_rn(__fadd_rn(__fmul_rn(dx, dx), __fmul_rn(dy, dy)), __fmul_rn(dz, dz)); \
    float nd = fminf(D##j, s); \
    D##j = nd; \
    if (nd >= bestd) { bestd = nd; besti = base + o; } }

__global__ __attribute__((amdgpu_flat_work_group_size(NTHR, NTHR)))
void fps_kernel(const float* __restrict__ depth, const float* __restrict__ rgb,
                float* __restrict__ out)
{
    const unsigned tid  = threadIdx.x;
    const unsigned lane = threadIdx.x & 63u;
    const unsigned wid  = threadIdx.x >> 6;
    const unsigned blk  = blockIdx.x;
    const unsigned base = blk << 13;            // first pixel owned by this block
    const float FINF = __int_as_float(0x7f800000);

    __shared__ float4 sP[PPB];                  // 128 KB immutable xyz
    __shared__ unsigned long long s_pp[NWAVE];
    __shared__ unsigned long long s_gp[4];
    __shared__ float              s_wd;         // winner depth broadcast
    __shared__ unsigned           s_widx[MAXP]; // block 0 only: selected indices

    FOR16(DECLD)

    // ---- init: project owned pixels into LDS (coalesced depth loads) ----
    #define INITJ(j) { \
        unsigned o   = tid + j##u * (unsigned)NTHR; \
        unsigned idx = base + o; \
        float x, y, z; \
        if (idx < NPIX) { \
            float d = depth[idx]; \
            float u = (float)(idx % WW); \
            float v = (float)(idx / WW); \
            bool val = (d > 0.1f) && (d < 2.0f) && __builtin_isfinite(d); \
            x = val ? proj_x(u, d) : FINF; \
            y = val ? proj_y(v, d) : FINF; \
            z = val ? d : FINF; \
            D##j = FINF; \
        } else { x = 0.f; y = 0.f; z = 0.f; D##j = -1.0f; } \
        sP[o] = make_float4(x, y, z, 0.0f); }
    FOR16(INITJ)

    if (tid == 0) s_widx[0] = 0u;
    __syncthreads();   // LDS xyz visible to all waves before iterating

    // first FPS point = flat index 0
    float px, py, pz;
    {
        float d = depth[0];
        bool val = (d > 0.1f) && (d < 2.0f) && __builtin_isfinite(d);
        px = val ? proj_x(0.0f, d) : FINF;
        py = val ? proj_y(0.0f, d) : FINF;
        pz = val ? d : FINF;
    }

    for (int it = 1; it < MAXP; ++it) {
        // ---- distance update (LDS xyz + register D) + thread-local argmax ----
        float bestd = -2.0f;
        unsigned besti = 0u;
        FOR16D(UPDJ)

        // 53-bit pack: never 0 for a real candidate (besti < NPIX < 0x1FFFFF)
        unsigned long long pk =
            ((unsigned long long)__float_as_uint(bestd) << 21) |
            (unsigned long long)(0x1FFFFFu - besti);

        // ---- wave reduce (u64 max) ----
        #pragma unroll
        for (int off = 32; off; off >>= 1) pk = umax64(pk, __shfl_xor(pk, off));
        if (lane == 0) s_pp[wid] = pk;
        __syncthreads();

        // ---- wave 0: block reduce + relaxed write-through store (no fences) ----
        if (wid == 0) {
            unsigned long long p2 = s_pp[lane & 7u];
            #pragma unroll
            for (int off = 4; off; off >>= 1) p2 = umax64(p2, __shfl_xor(p2, off));
            if (lane == 0)
                __hip_atomic_store(&g_packed[(size_t)it * NBLK + blk], p2,
                                   __ATOMIC_RELAXED, __HIP_MEMORY_SCOPE_AGENT);
        }

        // ---- one poll round: waves 0-3 poll all 254 slots (backoff spin) ----
        if (wid < 4) {
            unsigned slot = wid * 64u + lane;
            unsigned long long v = 0ull;
            if (slot < NBLK) {
                const unsigned long long* ap = &g_packed[(size_t)it * NBLK + slot];
                v = __hip_atomic_load(ap, __ATOMIC_RELAXED, __HIP_MEMORY_SCOPE_AGENT);
                while (v == 0ull) {
                    __builtin_amdgcn_s_sleep(2);
                    v = __hip_atomic_load(ap, __ATOMIC_RELAXED, __HIP_MEMORY_SCOPE_AGENT);
                }
            }
            #pragma unroll
            for (int off = 32; off; off >>= 1) v = umax64(v, __shfl_xor(v, off));
            if (lane == 0) s_gp[wid] = v;
        }
        __syncthreads();

        // ---- winner + single-lane depth fetch, LDS broadcast ----
        unsigned long long w = umax64(umax64(s_gp[0], s_gp[1]), umax64(s_gp[2], s_gp[3]));
        unsigned widx = 0x1FFFFFu - (unsigned)(w & 0x1FFFFFull);
        if (tid == 0) s_wd = depth[widx];
        if (blk == 0 && tid == 0) s_widx[it] = widx;
        __syncthreads();
        float wd = s_wd;

        float uu = (float)(widx % WW);
        float vv = (float)(widx / WW);
        bool val = (wd > 0.1f) && (wd < 2.0f) && __builtin_isfinite(wd);
        px = val ? proj_x(uu, wd) : FINF;
        py = val ? proj_y(vv, wd) : FINF;
        pz = val ? wd : FINF;
    }

    // ---- epilogue: block 0 gathers, normalizes, writes [2048,9] ----
    if (blk == 0) {
        __syncthreads();
        float ex[4], ey[4], ez[4], er[4], eg[4], eb[4];
        #pragma unroll
        for (int q = 0; q < 4; ++q) {
            int i = (int)tid + q * NTHR;
            unsigned sidx = s_widx[i];
            float d = depth[sidx];
            float u = (float)(sidx % WW);
            float v = (float)(sidx / WW);
            bool val = (d > 0.1f) && (d < 2.0f) && __builtin_isfinite(d);
            ex[q] = val ? proj_x(u, d) : FINF;
            ey[q] = val ? proj_y(v, d) : FINF;
            ez[q] = val ? d : FINF;
            er[q] = val ? __fdiv_rn(rgb[3u * sidx + 0u], 255.0f) : 0.0f;
            eg[q] = val ? __fdiv_rn(rgb[3u * sidx + 1u], 255.0f) : 0.0f;
            eb[q] = val ? __fdiv_rn(rgb[3u * sidx + 2u], 255.0f) : 0.0f;
        }
        float mn[3], mx[3];
        mn[0] = fminf(fminf(ex[0], ex[1]), fminf(ex[2], ex[3]));
        mx[0] = fmaxf(fmaxf(ex[0], ex[1]), fmaxf(ex[2], ex[3]));
        mn[1] = fminf(fminf(ey[0], ey[1]), fminf(ey[2], ey[3]));
        mx[1] = fmaxf(fmaxf(ey[0], ey[1]), fmaxf(ey[2], ey[3]));
        mn[2] = fminf(fminf(ez[0], ez[1]), fminf(ez[2], ez[3]));
        mx[2] = fmaxf(fmaxf(ez[0], ez[1]), fmaxf(ez[2], ez[3]));
        #pragma unroll
        for (int c = 0; c < 3; ++c) {
            for (int off = 32; off > 0; off >>= 1) {
                mn[c] = fminf(mn[c], __shfl_xor(mn[c], off));
                mx[c] = fmaxf(mx[c], __shfl_xor(mx[c], off));
            }
        }
        __shared__ float s_mn[NWAVE][3], s_mx[NWAVE][3];
        __shared__ float f_mn[3], f_sc[3];
        if (lane == 0) {
            for (int c = 0; c < 3; ++c) { s_mn[wid][c] = mn[c]; s_mx[wid][c] = mx[c]; }
        }
        __syncthreads();
        if (wid == 0) {
            float a[3], b[3];
            for (int c = 0; c < 3; ++c) {
                a[c] = (lane < NWAVE) ? s_mn[lane][c] : FINF;
                b[c] = (lane < NWAVE) ? s_mx[lane][c] : -FINF;
            }
            for (int off = NWAVE / 2; off > 0; off >>= 1) {
                for (int c = 0; c < 3; ++c) {
                    a[c] = fminf(a[c], __shfl_xor(a[c], off));
                    b[c] = fmaxf(b[c], __shfl_xor(b[c], off));
                }
            }
            if (lane == 0) {
                for (int c = 0; c < 3; ++c) {
                    f_mn[c] = a[c];
                    float m = __fsub_rn(b[c], a[c]);   // == max(centered) by monotonicity
                    f_sc[c] = (m < 1e-8f) ? 1.0f : m;
                }
            }
        }
        __syncthreads();
        float MN0 = f_mn[0], MN1 = f_mn[1], MN2 = f_mn[2];
        float SC0 = f_sc[0], SC1 = f_sc[1], SC2 = f_sc[2];
        #pragma unroll
        for (int q = 0; q < 4; ++q) {
            int i = (int)tid + q * NTHR;
            out[9 * i + 0] = ex[q];
            out[9 * i + 1] = ey[q];
            out[9 * i + 2] = ez[q];
            out[9 * i + 3] = er[q];
            out[9 * i + 4] = eg[q];
            out[9 * i + 5] = eb[q];
            out[9 * i + 6] = __fdiv_rn(__fsub_rn(ex[q], MN0), SC0);
            out[9 * i + 7] = __fdiv_rn(__fsub_rn(ey[q], MN1), SC1);
            out[9 * i + 8] = __fdiv_rn(__fsub_rn(ez[q], MN2), SC2);
        }
    }
}

extern "C" void kernel_launch(void* const* d_in, const int* in_sizes, int n_in,
                              void* d_out, int out_size, void* d_ws, size_t ws_size,
                              hipStream_t stream) {
    const float* depth = (const float*)d_in[0];
    const float* rgb   = (const float*)d_in[1];
    float* out = (float*)d_out;

    // re-initialize communication slots (deterministic per call / per graph replay)
    zero_ws_kernel<<<dim3((MAXP * NBLK + 255) / 256), dim3(256), 0, stream>>>();

    void* args[] = { (void*)&depth, (void*)&rgb, (void*)&out };
    hipLaunchCooperativeKernel((const void*)fps_kernel, dim3(NBLK), dim3(NTHR),
                               args, 0, stream);
}